// Round 1
// baseline (692.210 us; speedup 1.0000x reference)
//
#include <hip/hip_runtime.h>
#include <hip/hip_bf16.h>
#include <math.h>

#define N_NODES 50000
#define NEG_SLOPE 0.2f
#define EPS_DEN 1e-16f

// ---------------- GEMM + attention-logit kernel ----------------
// h[n, c] = sum_i x[n,i] * W[i*256 + c]   (c = head*64 + o)
// asrc[n,h] = sum_o h[n,h,o]*a_src[h,o];  adst likewise.
// Block = 256 threads (4 waves); wave w == head w; lane == o.
__global__ void __launch_bounds__(256) gemm_alpha_k(
    const float* __restrict__ x, const float* __restrict__ W,
    const float* __restrict__ aS, const float* __restrict__ aD,
    float* __restrict__ h, float* __restrict__ asrc, float* __restrict__ adst,
    int N)
{
    __shared__ float Wl[64 * 256];   // 64 KB
    __shared__ float asl[256];
    __shared__ float adl[256];
    __shared__ float xs[64];
    int tid = threadIdx.x;
    for (int i = tid; i < 64 * 256; i += 256) Wl[i] = W[i];
    asl[tid] = aS[tid];
    adl[tid] = aD[tid];
    __syncthreads();

    for (int n = blockIdx.x; n < N; n += gridDim.x) {
        if (tid < 64) xs[tid] = x[n * 64 + tid];
        __syncthreads();
        float acc = 0.f;
        #pragma unroll
        for (int i = 0; i < 64; ++i)
            acc = fmaf(xs[i], Wl[i * 256 + tid], acc);
        h[n * 256 + tid] = acc;

        float p1 = acc * asl[tid];
        float p2 = acc * adl[tid];
        #pragma unroll
        for (int off = 32; off >= 1; off >>= 1) {
            p1 += __shfl_xor(p1, off);
            p2 += __shfl_xor(p2, off);
        }
        if ((tid & 63) == 0) {
            int hd = tid >> 6;
            asrc[n * 4 + hd] = p1;
            adst[n * 4 + hd] = p2;
        }
        __syncthreads();
    }
}

// ---------------- CSR build ----------------
__global__ void zero_k(int* __restrict__ p, int n) {
    int i = blockIdx.x * blockDim.x + threadIdx.x;
    if (i < n) p[i] = 0;
}

__global__ void hist_k(const int* __restrict__ ei, int* __restrict__ cnt, int E) {
    int e = blockIdx.x * blockDim.x + threadIdx.x;
    if (e < E) atomicAdd(&cnt[ei[E + e]], 1);
}

// single-block exclusive scan over n counts -> row[0..n], cursor[i]=row[i]
__global__ void __launch_bounds__(1024) scan_k(
    const int* __restrict__ cnt, int* __restrict__ row, int* __restrict__ cursor, int n)
{
    __shared__ int sd[1024];
    __shared__ int carry;
    int tid = threadIdx.x;
    if (tid == 0) carry = 0;
    __syncthreads();
    for (int base = 0; base < n; base += 1024) {
        int i = base + tid;
        int v = (i < n) ? cnt[i] : 0;
        sd[tid] = v;
        __syncthreads();
        for (int off = 1; off < 1024; off <<= 1) {
            int t = (tid >= off) ? sd[tid - off] : 0;
            __syncthreads();
            sd[tid] += t;
            __syncthreads();
        }
        int total = sd[1023];
        int excl  = sd[tid] - v;
        int c = carry;
        if (i < n) { row[i] = c + excl; cursor[i] = c + excl; }
        __syncthreads();
        if (tid == 0) carry = c + total;
        __syncthreads();
    }
    if (tid == 0) row[n] = carry;
}

__global__ void scatter_k(const int* __restrict__ ei, int* __restrict__ cursor,
                          int* __restrict__ psrc, int E)
{
    int e = blockIdx.x * blockDim.x + threadIdx.x;
    if (e < E) {
        int d = ei[E + e];
        int pos = atomicAdd(&cursor[d], 1);
        psrc[pos] = ei[e];
    }
}

// ---------------- per-node softmax + aggregation ----------------
// one wave per node; lane = output channel o; 4 heads in registers.
__global__ void __launch_bounds__(256) aggregate_k(
    const float* __restrict__ h, const float* __restrict__ asrc,
    const float* __restrict__ adst, const int* __restrict__ row,
    const int* __restrict__ psrc, const float* __restrict__ bias,
    float* __restrict__ out, int N)
{
    int gw   = (blockIdx.x * 256 + threadIdx.x) >> 6;
    int lane = threadIdx.x & 63;
    if (gw >= N) return;
    int n  = gw;
    int rs = row[n], re = row[n + 1];

    float ad0 = adst[n * 4 + 0], ad1 = adst[n * 4 + 1];
    float ad2 = adst[n * 4 + 2], ad3 = adst[n * 4 + 3];

    // pass 1: segment max (lane-parallel over edges)
    float m0 = -INFINITY, m1 = -INFINITY, m2 = -INFINITY, m3 = -INFINITY;
    for (int idx = rs + lane; idx < re; idx += 64) {
        int s = psrc[idx];
        float e0 = asrc[s * 4 + 0] + ad0; e0 = e0 > 0.f ? e0 : NEG_SLOPE * e0;
        float e1 = asrc[s * 4 + 1] + ad1; e1 = e1 > 0.f ? e1 : NEG_SLOPE * e1;
        float e2 = asrc[s * 4 + 2] + ad2; e2 = e2 > 0.f ? e2 : NEG_SLOPE * e2;
        float e3 = asrc[s * 4 + 3] + ad3; e3 = e3 > 0.f ? e3 : NEG_SLOPE * e3;
        m0 = fmaxf(m0, e0); m1 = fmaxf(m1, e1);
        m2 = fmaxf(m2, e2); m3 = fmaxf(m3, e3);
    }
    #pragma unroll
    for (int off = 32; off >= 1; off >>= 1) {
        m0 = fmaxf(m0, __shfl_xor(m0, off));
        m1 = fmaxf(m1, __shfl_xor(m1, off));
        m2 = fmaxf(m2, __shfl_xor(m2, off));
        m3 = fmaxf(m3, __shfl_xor(m3, off));
    }

    // pass 2: segment sum of exp(e - m)
    float s0 = 0.f, s1 = 0.f, s2 = 0.f, s3 = 0.f;
    for (int idx = rs + lane; idx < re; idx += 64) {
        int s = psrc[idx];
        float e0 = asrc[s * 4 + 0] + ad0; e0 = e0 > 0.f ? e0 : NEG_SLOPE * e0;
        float e1 = asrc[s * 4 + 1] + ad1; e1 = e1 > 0.f ? e1 : NEG_SLOPE * e1;
        float e2 = asrc[s * 4 + 2] + ad2; e2 = e2 > 0.f ? e2 : NEG_SLOPE * e2;
        float e3 = asrc[s * 4 + 3] + ad3; e3 = e3 > 0.f ? e3 : NEG_SLOPE * e3;
        s0 += __expf(e0 - m0); s1 += __expf(e1 - m1);
        s2 += __expf(e2 - m2); s3 += __expf(e3 - m3);
    }
    #pragma unroll
    for (int off = 32; off >= 1; off >>= 1) {
        s0 += __shfl_xor(s0, off);
        s1 += __shfl_xor(s1, off);
        s2 += __shfl_xor(s2, off);
        s3 += __shfl_xor(s3, off);
    }
    float i0 = 1.f / (s0 + EPS_DEN), i1 = 1.f / (s1 + EPS_DEN);
    float i2 = 1.f / (s2 + EPS_DEN), i3 = 1.f / (s3 + EPS_DEN);

    // pass 3: weighted gather of h[src]; lane = o channel
    float a0 = 0.f, a1 = 0.f, a2 = 0.f, a3 = 0.f;
    for (int idx = rs; idx < re; ++idx) {
        int s = psrc[idx];
        float e0 = asrc[s * 4 + 0] + ad0; e0 = e0 > 0.f ? e0 : NEG_SLOPE * e0;
        float e1 = asrc[s * 4 + 1] + ad1; e1 = e1 > 0.f ? e1 : NEG_SLOPE * e1;
        float e2 = asrc[s * 4 + 2] + ad2; e2 = e2 > 0.f ? e2 : NEG_SLOPE * e2;
        float e3 = asrc[s * 4 + 3] + ad3; e3 = e3 > 0.f ? e3 : NEG_SLOPE * e3;
        float w0 = __expf(e0 - m0) * i0;
        float w1 = __expf(e1 - m1) * i1;
        float w2 = __expf(e2 - m2) * i2;
        float w3 = __expf(e3 - m3) * i3;
        const float* hp = h + (size_t)s * 256;
        a0 = fmaf(w0, hp[lane],       a0);
        a1 = fmaf(w1, hp[64 + lane],  a1);
        a2 = fmaf(w2, hp[128 + lane], a2);
        a3 = fmaf(w3, hp[192 + lane], a3);
    }
    float o = (a0 + a1 + a2 + a3) * 0.25f + bias[lane];
    out[n * 64 + lane] = fmaxf(o, 0.f);
}

// ---------------- launch ----------------
extern "C" void kernel_launch(void* const* d_in, const int* in_sizes, int n_in,
                              void* d_out, int out_size, void* d_ws, size_t ws_size,
                              hipStream_t stream)
{
    const float* x   = (const float*)d_in[0];
    const int*   ei  = (const int*)d_in[1];   // [2, E] int32
    const float* W1  = (const float*)d_in[4];
    const float* as1 = (const float*)d_in[5];
    const float* ad1 = (const float*)d_in[6];
    const float* b1  = (const float*)d_in[7];
    const float* W2  = (const float*)d_in[8];
    const float* as2 = (const float*)d_in[9];
    const float* ad2 = (const float*)d_in[10];
    const float* b2  = (const float*)d_in[11];

    const int E = in_sizes[1] / 2;
    const int N = N_NODES;

    char* ws = (char*)d_ws;
    size_t off = 0;
    auto alloc = [&](size_t bytes) -> void* {
        void* p = ws + off;
        off = (off + bytes + 255) & ~(size_t)255;
        return p;
    };
    float* h      = (float*)alloc((size_t)N * 256 * 4);  // 51.2 MB
    float* x1     = (float*)alloc((size_t)N * 64 * 4);   // 12.8 MB
    float* asrc   = (float*)alloc((size_t)N * 4 * 4);
    float* adst   = (float*)alloc((size_t)N * 4 * 4);
    int*   cnt    = (int*)alloc((size_t)N * 4);
    int*   row    = (int*)alloc((size_t)(N + 1) * 4);
    int*   cursor = (int*)alloc((size_t)N * 4);
    int*   psrc   = (int*)alloc((size_t)E * 4);          // 3.2 MB

    // CSR by dst (shared across both layers)
    zero_k<<<(N + 255) / 256, 256, 0, stream>>>(cnt, N);
    hist_k<<<(E + 255) / 256, 256, 0, stream>>>(ei, cnt, E);
    scan_k<<<1, 1024, 0, stream>>>(cnt, row, cursor, N);
    scatter_k<<<(E + 255) / 256, 256, 0, stream>>>(ei, cursor, psrc, E);

    // layer 1
    gemm_alpha_k<<<512, 256, 0, stream>>>(x, W1, as1, ad1, h, asrc, adst, N);
    aggregate_k<<<(N + 3) / 4, 256, 0, stream>>>(h, asrc, adst, row, psrc, b1, x1, N);

    // layer 2
    gemm_alpha_k<<<512, 256, 0, stream>>>(x1, W2, as2, ad2, h, asrc, adst, N);
    aggregate_k<<<(N + 3) / 4, 256, 0, stream>>>(h, asrc, adst, row, psrc, b2, (float*)d_out, N);
}

// Round 2
// 523.859 us; speedup vs baseline: 1.3214x; 1.3214x over previous
//
#include <hip/hip_runtime.h>
#include <hip/hip_bf16.h>
#include <math.h>

#define N_NODES 50000
#define NEG_SLOPE 0.2f
#define EPS_DEN 1e-16f

// ---------------- tiled GEMM + attention-logit kernel ----------------
// h[n, c] = sum_i x[n,i] * W[i*256 + c]   (c = head*64 + o)
// Tile: 128 nodes x 128 cols (= 2 heads) per block, 256 threads,
// 8x8 outputs per thread. x-tile transposed + XOR-swizzled in LDS so the
// k-loop is 4x ds_read_b128 per 64 FMAs, conflict-free.
__global__ void __launch_bounds__(256) gemm_alpha2_k(
    const float* __restrict__ x, const float* __restrict__ W,
    const float* __restrict__ aS, const float* __restrict__ aD,
    float* __restrict__ h, float* __restrict__ asrc, float* __restrict__ adst,
    int N)
{
    __shared__ float xsT[64 * 128];  // [k][n^swz] 32 KB
    __shared__ float Ws [64 * 128];  // [k][c]     32 KB
    const int tid = threadIdx.x;
    const int n0  = blockIdx.x * 128;
    const int hb  = blockIdx.y;          // 0/1 -> cols hb*128 .. +127

    // W tile: rows k=0..63, cols hb*128 + 0..127 (row stride 256)
    #pragma unroll
    for (int it = 0; it < 8; ++it) {
        int idx = tid + 256 * it;            // 0..2047 float4s
        int k   = idx >> 5;                  // 32 float4 per row
        int c4  = (idx & 31) << 2;
        *(float4*)(Ws + k * 128 + c4) =
            *(const float4*)(W + k * 256 + hb * 128 + c4);
    }
    // x tile, transposed into xsT[k][n ^ (4*((k>>2)&7))]
    #pragma unroll
    for (int it = 0; it < 8; ++it) {
        int idx = tid + 256 * it;            // 0..2047 float4s
        int n   = idx >> 4;                  // 16 float4 per row of x
        int k4  = (idx & 15) << 2;
        int gn  = n0 + n;
        float4 v = make_float4(0.f, 0.f, 0.f, 0.f);
        if (gn < N) v = *(const float4*)(x + (size_t)gn * 64 + k4);
        int nsw = n ^ (((k4 >> 2) & 7) << 2);
        xsT[(k4 + 0) * 128 + nsw] = v.x;
        xsT[(k4 + 1) * 128 + nsw] = v.y;
        xsT[(k4 + 2) * 128 + nsw] = v.z;
        xsT[(k4 + 3) * 128 + nsw] = v.w;
    }
    __syncthreads();

    const int rgrp = tid >> 4;               // 16 row groups
    const int cgrp = tid & 15;               // 16 col groups
    const int r8 = rgrp << 3, c8 = cgrp << 3;

    float acc[8][8];
    #pragma unroll
    for (int i = 0; i < 8; ++i)
        #pragma unroll
        for (int j = 0; j < 8; ++j) acc[i][j] = 0.f;

    #pragma unroll 8
    for (int k = 0; k < 64; ++k) {
        int sw = ((k >> 2) & 7) << 2;
        int xb0 = r8 ^ sw;
        float4 xa = *(const float4*)(xsT + k * 128 + xb0);
        float4 xb = *(const float4*)(xsT + k * 128 + (xb0 ^ 4));
        float4 wa = *(const float4*)(Ws  + k * 128 + c8);
        float4 wb = *(const float4*)(Ws  + k * 128 + c8 + 4);
        float xr[8] = {xa.x, xa.y, xa.z, xa.w, xb.x, xb.y, xb.z, xb.w};
        float wc[8] = {wa.x, wa.y, wa.z, wa.w, wb.x, wb.y, wb.z, wb.w};
        #pragma unroll
        for (int i = 0; i < 8; ++i)
            #pragma unroll
            for (int j = 0; j < 8; ++j)
                acc[i][j] = fmaf(xr[i], wc[j], acc[i][j]);
    }

    // epilogue: store h, reduce alpha_src/alpha_dst per (row, head)
    const int col0 = hb * 128 + c8;          // global col base
    const int head = col0 >> 6;              // 8 cols never cross a head
    float as_[8], ad_[8];
    #pragma unroll
    for (int j = 0; j < 8; ++j) { as_[j] = aS[col0 + j]; ad_[j] = aD[col0 + j]; }

    #pragma unroll
    for (int i = 0; i < 8; ++i) {
        int gn = n0 + r8 + i;
        bool ok = gn < N;
        if (ok) {
            float4 h0 = make_float4(acc[i][0], acc[i][1], acc[i][2], acc[i][3]);
            float4 h1 = make_float4(acc[i][4], acc[i][5], acc[i][6], acc[i][7]);
            *(float4*)(h + (size_t)gn * 256 + col0)     = h0;
            *(float4*)(h + (size_t)gn * 256 + col0 + 4) = h1;
        }
        float pa = 0.f, pd = 0.f;
        #pragma unroll
        for (int j = 0; j < 8; ++j) {
            pa = fmaf(acc[i][j], as_[j], pa);
            pd = fmaf(acc[i][j], ad_[j], pd);
        }
        pa += __shfl_xor(pa, 1); pd += __shfl_xor(pd, 1);
        pa += __shfl_xor(pa, 2); pd += __shfl_xor(pd, 2);
        pa += __shfl_xor(pa, 4); pd += __shfl_xor(pd, 4);
        if (ok && (cgrp & 7) == 0) {
            asrc[gn * 4 + head] = pa;
            adst[gn * 4 + head] = pd;
        }
    }
}

// ---------------- CSR build ----------------
__global__ void zero_k(int* __restrict__ p, int n) {
    int i = blockIdx.x * blockDim.x + threadIdx.x;
    if (i < n) p[i] = 0;
}

__global__ void hist_k(const int* __restrict__ ei, int* __restrict__ cnt, int E) {
    int e = blockIdx.x * blockDim.x + threadIdx.x;
    if (e < E) atomicAdd(&cnt[ei[E + e]], 1);
}

__global__ void __launch_bounds__(1024) scan_k(
    const int* __restrict__ cnt, int* __restrict__ row, int* __restrict__ cursor, int n)
{
    __shared__ int sd[1024];
    __shared__ int carry;
    int tid = threadIdx.x;
    if (tid == 0) carry = 0;
    __syncthreads();
    for (int base = 0; base < n; base += 1024) {
        int i = base + tid;
        int v = (i < n) ? cnt[i] : 0;
        sd[tid] = v;
        __syncthreads();
        for (int off = 1; off < 1024; off <<= 1) {
            int t = (tid >= off) ? sd[tid - off] : 0;
            __syncthreads();
            sd[tid] += t;
            __syncthreads();
        }
        int total = sd[1023];
        int excl  = sd[tid] - v;
        int c = carry;
        if (i < n) { row[i] = c + excl; cursor[i] = c + excl; }
        __syncthreads();
        if (tid == 0) carry = c + total;
        __syncthreads();
    }
    if (tid == 0) row[n] = carry;
}

__global__ void scatter_k(const int* __restrict__ ei, int* __restrict__ cursor,
                          int* __restrict__ psrc, int E)
{
    int e = blockIdx.x * blockDim.x + threadIdx.x;
    if (e < E) {
        int d = ei[E + e];
        int pos = atomicAdd(&cursor[d], 1);
        psrc[pos] = ei[e];
    }
}

// ---------------- per-node softmax + aggregation ----------------
__global__ void __launch_bounds__(256) aggregate_k(
    const float* __restrict__ h, const float* __restrict__ asrc,
    const float* __restrict__ adst, const int* __restrict__ row,
    const int* __restrict__ psrc, const float* __restrict__ bias,
    float* __restrict__ out, int N)
{
    int gw   = (blockIdx.x * 256 + threadIdx.x) >> 6;
    int lane = threadIdx.x & 63;
    if (gw >= N) return;
    int n  = gw;
    int rs = row[n], re = row[n + 1];

    float ad0 = adst[n * 4 + 0], ad1 = adst[n * 4 + 1];
    float ad2 = adst[n * 4 + 2], ad3 = adst[n * 4 + 3];

    float m0 = -INFINITY, m1 = -INFINITY, m2 = -INFINITY, m3 = -INFINITY;
    for (int idx = rs + lane; idx < re; idx += 64) {
        int s = psrc[idx];
        float e0 = asrc[s * 4 + 0] + ad0; e0 = e0 > 0.f ? e0 : NEG_SLOPE * e0;
        float e1 = asrc[s * 4 + 1] + ad1; e1 = e1 > 0.f ? e1 : NEG_SLOPE * e1;
        float e2 = asrc[s * 4 + 2] + ad2; e2 = e2 > 0.f ? e2 : NEG_SLOPE * e2;
        float e3 = asrc[s * 4 + 3] + ad3; e3 = e3 > 0.f ? e3 : NEG_SLOPE * e3;
        m0 = fmaxf(m0, e0); m1 = fmaxf(m1, e1);
        m2 = fmaxf(m2, e2); m3 = fmaxf(m3, e3);
    }
    #pragma unroll
    for (int off = 32; off >= 1; off >>= 1) {
        m0 = fmaxf(m0, __shfl_xor(m0, off));
        m1 = fmaxf(m1, __shfl_xor(m1, off));
        m2 = fmaxf(m2, __shfl_xor(m2, off));
        m3 = fmaxf(m3, __shfl_xor(m3, off));
    }

    float s0 = 0.f, s1 = 0.f, s2 = 0.f, s3 = 0.f;
    for (int idx = rs + lane; idx < re; idx += 64) {
        int s = psrc[idx];
        float e0 = asrc[s * 4 + 0] + ad0; e0 = e0 > 0.f ? e0 : NEG_SLOPE * e0;
        float e1 = asrc[s * 4 + 1] + ad1; e1 = e1 > 0.f ? e1 : NEG_SLOPE * e1;
        float e2 = asrc[s * 4 + 2] + ad2; e2 = e2 > 0.f ? e2 : NEG_SLOPE * e2;
        float e3 = asrc[s * 4 + 3] + ad3; e3 = e3 > 0.f ? e3 : NEG_SLOPE * e3;
        s0 += __expf(e0 - m0); s1 += __expf(e1 - m1);
        s2 += __expf(e2 - m2); s3 += __expf(e3 - m3);
    }
    #pragma unroll
    for (int off = 32; off >= 1; off >>= 1) {
        s0 += __shfl_xor(s0, off);
        s1 += __shfl_xor(s1, off);
        s2 += __shfl_xor(s2, off);
        s3 += __shfl_xor(s3, off);
    }
    float i0 = 1.f / (s0 + EPS_DEN), i1 = 1.f / (s1 + EPS_DEN);
    float i2 = 1.f / (s2 + EPS_DEN), i3 = 1.f / (s3 + EPS_DEN);

    float a0 = 0.f, a1 = 0.f, a2 = 0.f, a3 = 0.f;
    for (int idx = rs; idx < re; ++idx) {
        int s = psrc[idx];
        float e0 = asrc[s * 4 + 0] + ad0; e0 = e0 > 0.f ? e0 : NEG_SLOPE * e0;
        float e1 = asrc[s * 4 + 1] + ad1; e1 = e1 > 0.f ? e1 : NEG_SLOPE * e1;
        float e2 = asrc[s * 4 + 2] + ad2; e2 = e2 > 0.f ? e2 : NEG_SLOPE * e2;
        float e3 = asrc[s * 4 + 3] + ad3; e3 = e3 > 0.f ? e3 : NEG_SLOPE * e3;
        float w0 = __expf(e0 - m0) * i0;
        float w1 = __expf(e1 - m1) * i1;
        float w2 = __expf(e2 - m2) * i2;
        float w3 = __expf(e3 - m3) * i3;
        const float* hp = h + (size_t)s * 256;
        a0 = fmaf(w0, hp[lane],       a0);
        a1 = fmaf(w1, hp[64 + lane],  a1);
        a2 = fmaf(w2, hp[128 + lane], a2);
        a3 = fmaf(w3, hp[192 + lane], a3);
    }
    float o = (a0 + a1 + a2 + a3) * 0.25f + bias[lane];
    out[n * 64 + lane] = fmaxf(o, 0.f);
}

// ---------------- launch ----------------
extern "C" void kernel_launch(void* const* d_in, const int* in_sizes, int n_in,
                              void* d_out, int out_size, void* d_ws, size_t ws_size,
                              hipStream_t stream)
{
    const float* x   = (const float*)d_in[0];
    const int*   ei  = (const int*)d_in[1];   // [2, E] int32
    const float* W1  = (const float*)d_in[4];
    const float* as1 = (const float*)d_in[5];
    const float* ad1 = (const float*)d_in[6];
    const float* b1  = (const float*)d_in[7];
    const float* W2  = (const float*)d_in[8];
    const float* as2 = (const float*)d_in[9];
    const float* ad2 = (const float*)d_in[10];
    const float* b2  = (const float*)d_in[11];

    const int E = in_sizes[1] / 2;
    const int N = N_NODES;

    char* ws = (char*)d_ws;
    size_t off = 0;
    auto alloc = [&](size_t bytes) -> void* {
        void* p = ws + off;
        off = (off + bytes + 255) & ~(size_t)255;
        return p;
    };
    float* h      = (float*)alloc((size_t)N * 256 * 4);
    float* x1     = (float*)alloc((size_t)N * 64 * 4);
    float* asrc   = (float*)alloc((size_t)N * 4 * 4);
    float* adst   = (float*)alloc((size_t)N * 4 * 4);
    int*   cnt    = (int*)alloc((size_t)N * 4);
    int*   row    = (int*)alloc((size_t)(N + 1) * 4);
    int*   cursor = (int*)alloc((size_t)N * 4);
    int*   psrc   = (int*)alloc((size_t)E * 4);

    zero_k<<<(N + 255) / 256, 256, 0, stream>>>(cnt, N);
    hist_k<<<(E + 255) / 256, 256, 0, stream>>>(ei, cnt, E);
    scan_k<<<1, 1024, 0, stream>>>(cnt, row, cursor, N);
    scatter_k<<<(E + 255) / 256, 256, 0, stream>>>(ei, cursor, psrc, E);

    dim3 ggrid((N + 127) / 128, 2);

    gemm_alpha2_k<<<ggrid, 256, 0, stream>>>(x, W1, as1, ad1, h, asrc, adst, N);
    aggregate_k<<<(N + 3) / 4, 256, 0, stream>>>(h, asrc, adst, row, psrc, b1, x1, N);

    gemm_alpha2_k<<<ggrid, 256, 0, stream>>>(x1, W2, as2, ad2, h, asrc, adst, N);
    aggregate_k<<<(N + 3) / 4, 256, 0, stream>>>(h, asrc, adst, row, psrc, b2, (float*)d_out, N);
}

// Round 3
// 418.644 us; speedup vs baseline: 1.6535x; 1.2513x over previous
//
#include <hip/hip_runtime.h>
#include <hip/hip_bf16.h>
#include <math.h>

#define N_NODES 50000
#define NEG_SLOPE 0.2f
#define EPS_DEN 1e-16f

// ---------------- tiled GEMM + attention-logit kernel ----------------
__global__ void __launch_bounds__(256) gemm_alpha2_k(
    const float* __restrict__ x, const float* __restrict__ W,
    const float* __restrict__ aS, const float* __restrict__ aD,
    float* __restrict__ h, float* __restrict__ asrc, float* __restrict__ adst,
    int N)
{
    __shared__ float xsT[64 * 128];  // [k][n^swz] 32 KB
    __shared__ float Ws [64 * 128];  // [k][c]     32 KB
    const int tid = threadIdx.x;
    const int n0  = blockIdx.x * 128;
    const int hb  = blockIdx.y;

    #pragma unroll
    for (int it = 0; it < 8; ++it) {
        int idx = tid + 256 * it;
        int k   = idx >> 5;
        int c4  = (idx & 31) << 2;
        *(float4*)(Ws + k * 128 + c4) =
            *(const float4*)(W + k * 256 + hb * 128 + c4);
    }
    #pragma unroll
    for (int it = 0; it < 8; ++it) {
        int idx = tid + 256 * it;
        int n   = idx >> 4;
        int k4  = (idx & 15) << 2;
        int gn  = n0 + n;
        float4 v = make_float4(0.f, 0.f, 0.f, 0.f);
        if (gn < N) v = *(const float4*)(x + (size_t)gn * 64 + k4);
        int nsw = n ^ (((k4 >> 2) & 7) << 2);
        xsT[(k4 + 0) * 128 + nsw] = v.x;
        xsT[(k4 + 1) * 128 + nsw] = v.y;
        xsT[(k4 + 2) * 128 + nsw] = v.z;
        xsT[(k4 + 3) * 128 + nsw] = v.w;
    }
    __syncthreads();

    const int rgrp = tid >> 4;
    const int cgrp = tid & 15;
    const int r8 = rgrp << 3, c8 = cgrp << 3;

    float acc[8][8];
    #pragma unroll
    for (int i = 0; i < 8; ++i)
        #pragma unroll
        for (int j = 0; j < 8; ++j) acc[i][j] = 0.f;

    #pragma unroll 8
    for (int k = 0; k < 64; ++k) {
        int sw = ((k >> 2) & 7) << 2;
        int xb0 = r8 ^ sw;
        float4 xa = *(const float4*)(xsT + k * 128 + xb0);
        float4 xb = *(const float4*)(xsT + k * 128 + (xb0 ^ 4));
        float4 wa = *(const float4*)(Ws  + k * 128 + c8);
        float4 wb = *(const float4*)(Ws  + k * 128 + c8 + 4);
        float xr[8] = {xa.x, xa.y, xa.z, xa.w, xb.x, xb.y, xb.z, xb.w};
        float wc[8] = {wa.x, wa.y, wa.z, wa.w, wb.x, wb.y, wb.z, wb.w};
        #pragma unroll
        for (int i = 0; i < 8; ++i)
            #pragma unroll
            for (int j = 0; j < 8; ++j)
                acc[i][j] = fmaf(xr[i], wc[j], acc[i][j]);
    }

    const int col0 = hb * 128 + c8;
    const int head = col0 >> 6;
    float as_[8], ad_[8];
    #pragma unroll
    for (int j = 0; j < 8; ++j) { as_[j] = aS[col0 + j]; ad_[j] = aD[col0 + j]; }

    #pragma unroll
    for (int i = 0; i < 8; ++i) {
        int gn = n0 + r8 + i;
        bool ok = gn < N;
        if (ok) {
            float4 h0 = make_float4(acc[i][0], acc[i][1], acc[i][2], acc[i][3]);
            float4 h1 = make_float4(acc[i][4], acc[i][5], acc[i][6], acc[i][7]);
            *(float4*)(h + (size_t)gn * 256 + col0)     = h0;
            *(float4*)(h + (size_t)gn * 256 + col0 + 4) = h1;
        }
        float pa = 0.f, pd = 0.f;
        #pragma unroll
        for (int j = 0; j < 8; ++j) {
            pa = fmaf(acc[i][j], as_[j], pa);
            pd = fmaf(acc[i][j], ad_[j], pd);
        }
        pa += __shfl_xor(pa, 1); pd += __shfl_xor(pd, 1);
        pa += __shfl_xor(pa, 2); pd += __shfl_xor(pd, 2);
        pa += __shfl_xor(pa, 4); pd += __shfl_xor(pd, 4);
        if (ok && (cgrp & 7) == 0) {
            asrc[gn * 4 + head] = pa;
            adst[gn * 4 + head] = pd;
        }
    }
}

// ---------------- CSR build ----------------
__global__ void zero_k(int* __restrict__ p, int n) {
    int i = blockIdx.x * blockDim.x + threadIdx.x;
    if (i < n) p[i] = 0;
}

__global__ void hist_k(const int* __restrict__ ei, int* __restrict__ cnt, int E) {
    int e = blockIdx.x * blockDim.x + threadIdx.x;
    if (e < E) atomicAdd(&cnt[ei[E + e]], 1);
}

// two-level scan: scan1 (per-block), scan2 (block sums, serial), scan3 (add)
__global__ void __launch_bounds__(1024) scan1_k(
    const int* __restrict__ cnt, int* __restrict__ excl, int* __restrict__ bsum, int n)
{
    __shared__ int sd[1024];
    int tid = threadIdx.x;
    int i = blockIdx.x * 1024 + tid;
    int v = (i < n) ? cnt[i] : 0;
    sd[tid] = v;
    __syncthreads();
    for (int off = 1; off < 1024; off <<= 1) {
        int t = (tid >= off) ? sd[tid - off] : 0;
        __syncthreads();
        sd[tid] += t;
        __syncthreads();
    }
    if (i < n) excl[i] = sd[tid] - v;
    if (tid == 1023) bsum[blockIdx.x] = sd[1023];
}

__global__ void scan2_k(int* __restrict__ bsum, int nb) {
    if (threadIdx.x == 0 && blockIdx.x == 0) {
        int acc = 0;
        for (int i = 0; i < nb; ++i) { int t = bsum[i]; bsum[i] = acc; acc += t; }
    }
}

__global__ void scan3_k(const int* __restrict__ excl, const int* __restrict__ bsum,
                        int* __restrict__ row, int* __restrict__ cursor, int n, int E)
{
    int i = blockIdx.x * blockDim.x + threadIdx.x;
    if (i < n) {
        int r = excl[i] + bsum[i >> 10];
        row[i] = r;
        cursor[i] = r;
    }
    if (i == n) row[n] = E;
}

__global__ void scatter_k(const int* __restrict__ ei, int* __restrict__ cursor,
                          int* __restrict__ psrc, int E)
{
    int e = blockIdx.x * blockDim.x + threadIdx.x;
    if (e < E) {
        int d = ei[E + e];
        int pos = atomicAdd(&cursor[d], 1);
        psrc[pos] = ei[e];
    }
}

// ---------------- per-node softmax + aggregation (v2) ----------------
// one wave per node; edge weights staged in LDS; gather as lane-striped float4.
// lane L covers output channels 4L..4L+3, i.e. head = L>>4, o = 4*(L&15)..+3.
#define MAXDEG 256
__global__ void __launch_bounds__(256) aggregate2_k(
    const float* __restrict__ h, const float* __restrict__ asrc,
    const float* __restrict__ adst, const int* __restrict__ row,
    const int* __restrict__ psrc, const float* __restrict__ bias,
    float* __restrict__ out, int N)
{
    __shared__ float4 pL[4][MAXDEG];   // 16 KB
    const int wid  = threadIdx.x >> 6;
    const int lane = threadIdx.x & 63;
    const int n = blockIdx.x * 4 + wid;
    if (n >= N) return;
    const int rs = row[n], re = row[n + 1];
    const int deg = re - rs;

    const float4 ad = *(const float4*)(adst + 4 * (size_t)n);
    const int head = lane >> 4;
    float4 bias4 = *(const float4*)(bias + 4 * (lane & 15));

    float m0 = -INFINITY, m1 = -INFINITY, m2 = -INFINITY, m3 = -INFINITY;
    float s0 = 0.f, s1 = 0.f, s2 = 0.f, s3 = 0.f;

    if (deg <= MAXDEG) {
        // pass A: logits -> LDS, lane-local max
        for (int j = lane; j < deg; j += 64) {
            int s = psrc[rs + j];
            float4 a = *(const float4*)(asrc + 4 * (size_t)s);
            float e0 = a.x + ad.x; e0 = e0 > 0.f ? e0 : NEG_SLOPE * e0;
            float e1 = a.y + ad.y; e1 = e1 > 0.f ? e1 : NEG_SLOPE * e1;
            float e2 = a.z + ad.z; e2 = e2 > 0.f ? e2 : NEG_SLOPE * e2;
            float e3 = a.w + ad.w; e3 = e3 > 0.f ? e3 : NEG_SLOPE * e3;
            pL[wid][j] = make_float4(e0, e1, e2, e3);
            m0 = fmaxf(m0, e0); m1 = fmaxf(m1, e1);
            m2 = fmaxf(m2, e2); m3 = fmaxf(m3, e3);
        }
        #pragma unroll
        for (int off = 32; off >= 1; off >>= 1) {
            m0 = fmaxf(m0, __shfl_xor(m0, off));
            m1 = fmaxf(m1, __shfl_xor(m1, off));
            m2 = fmaxf(m2, __shfl_xor(m2, off));
            m3 = fmaxf(m3, __shfl_xor(m3, off));
        }
        // pass A2: e -> p = exp(e-m) in LDS, lane-local sum
        for (int j = lane; j < deg; j += 64) {
            float4 e = pL[wid][j];
            float4 p = make_float4(__expf(e.x - m0), __expf(e.y - m1),
                                   __expf(e.z - m2), __expf(e.w - m3));
            pL[wid][j] = p;
            s0 += p.x; s1 += p.y; s2 += p.z; s3 += p.w;
        }
        #pragma unroll
        for (int off = 32; off >= 1; off >>= 1) {
            s0 += __shfl_xor(s0, off);
            s1 += __shfl_xor(s1, off);
            s2 += __shfl_xor(s2, off);
            s3 += __shfl_xor(s3, off);
        }
    } else {
        // fallback (never taken for Poisson(16) degrees): recompute paths
        for (int idx = rs + lane; idx < re; idx += 64) {
            int s = psrc[idx];
            float4 a = *(const float4*)(asrc + 4 * (size_t)s);
            float e0 = a.x + ad.x; e0 = e0 > 0.f ? e0 : NEG_SLOPE * e0;
            float e1 = a.y + ad.y; e1 = e1 > 0.f ? e1 : NEG_SLOPE * e1;
            float e2 = a.z + ad.z; e2 = e2 > 0.f ? e2 : NEG_SLOPE * e2;
            float e3 = a.w + ad.w; e3 = e3 > 0.f ? e3 : NEG_SLOPE * e3;
            m0 = fmaxf(m0, e0); m1 = fmaxf(m1, e1);
            m2 = fmaxf(m2, e2); m3 = fmaxf(m3, e3);
        }
        #pragma unroll
        for (int off = 32; off >= 1; off >>= 1) {
            m0 = fmaxf(m0, __shfl_xor(m0, off));
            m1 = fmaxf(m1, __shfl_xor(m1, off));
            m2 = fmaxf(m2, __shfl_xor(m2, off));
            m3 = fmaxf(m3, __shfl_xor(m3, off));
        }
        for (int idx = rs + lane; idx < re; idx += 64) {
            int s = psrc[idx];
            float4 a = *(const float4*)(asrc + 4 * (size_t)s);
            float e0 = a.x + ad.x; e0 = e0 > 0.f ? e0 : NEG_SLOPE * e0;
            float e1 = a.y + ad.y; e1 = e1 > 0.f ? e1 : NEG_SLOPE * e1;
            float e2 = a.z + ad.z; e2 = e2 > 0.f ? e2 : NEG_SLOPE * e2;
            float e3 = a.w + ad.w; e3 = e3 > 0.f ? e3 : NEG_SLOPE * e3;
            s0 += __expf(e0 - m0); s1 += __expf(e1 - m1);
            s2 += __expf(e2 - m2); s3 += __expf(e3 - m3);
        }
        #pragma unroll
        for (int off = 32; off >= 1; off >>= 1) {
            s0 += __shfl_xor(s0, off);
            s1 += __shfl_xor(s1, off);
            s2 += __shfl_xor(s2, off);
            s3 += __shfl_xor(s3, off);
        }
    }

    float i0 = 1.f / (s0 + EPS_DEN), i1 = 1.f / (s1 + EPS_DEN);
    float i2 = 1.f / (s2 + EPS_DEN), i3 = 1.f / (s3 + EPS_DEN);
    float inv_lane = (head & 2) ? ((head & 1) ? i3 : i2)
                                : ((head & 1) ? i1 : i0);

    // pass B: weighted gather, lane-striped float4 over the h row
    float ax = 0.f, ay = 0.f, az = 0.f, aw = 0.f;
    const float* hbase = h + (size_t)lane * 4;

    if (deg <= MAXDEG) {
        int j = 0;
        for (; j + 4 <= deg; j += 4) {
            #pragma unroll
            for (int u = 0; u < 4; ++u) {
                int s = psrc[rs + j + u];
                float4 p = pL[wid][j + u];
                float w = (head & 2) ? ((head & 1) ? p.w : p.z)
                                     : ((head & 1) ? p.y : p.x);
                float4 v = *(const float4*)(hbase + (size_t)s * 256);
                ax = fmaf(w, v.x, ax); ay = fmaf(w, v.y, ay);
                az = fmaf(w, v.z, az); aw = fmaf(w, v.w, aw);
            }
        }
        for (; j < deg; ++j) {
            int s = psrc[rs + j];
            float4 p = pL[wid][j];
            float w = (head & 2) ? ((head & 1) ? p.w : p.z)
                                 : ((head & 1) ? p.y : p.x);
            float4 v = *(const float4*)(hbase + (size_t)s * 256);
            ax = fmaf(w, v.x, ax); ay = fmaf(w, v.y, ay);
            az = fmaf(w, v.z, az); aw = fmaf(w, v.w, aw);
        }
    } else {
        for (int idx = rs; idx < re; ++idx) {
            int s = psrc[idx];
            float4 a = *(const float4*)(asrc + 4 * (size_t)s);
            float e0 = a.x + ad.x; e0 = e0 > 0.f ? e0 : NEG_SLOPE * e0;
            float e1 = a.y + ad.y; e1 = e1 > 0.f ? e1 : NEG_SLOPE * e1;
            float e2 = a.z + ad.z; e2 = e2 > 0.f ? e2 : NEG_SLOPE * e2;
            float e3 = a.w + ad.w; e3 = e3 > 0.f ? e3 : NEG_SLOPE * e3;
            float p0 = __expf(e0 - m0), p1 = __expf(e1 - m1);
            float p2 = __expf(e2 - m2), p3 = __expf(e3 - m3);
            float w = (head & 2) ? ((head & 1) ? p3 : p2)
                                 : ((head & 1) ? p1 : p0);
            float4 v = *(const float4*)(hbase + (size_t)s * 256);
            ax = fmaf(w, v.x, ax); ay = fmaf(w, v.y, ay);
            az = fmaf(w, v.z, az); aw = fmaf(w, v.w, aw);
        }
    }

    ax *= inv_lane; ay *= inv_lane; az *= inv_lane; aw *= inv_lane;
    // sum over heads: lanes {L, L^16, L^32, L^48}
    #pragma unroll
    for (int off = 16; off <= 32; off <<= 1) {
        ax += __shfl_xor(ax, off);
        ay += __shfl_xor(ay, off);
        az += __shfl_xor(az, off);
        aw += __shfl_xor(aw, off);
    }
    if (lane < 16) {
        float4 o;
        o.x = fmaxf(ax * 0.25f + bias4.x, 0.f);
        o.y = fmaxf(ay * 0.25f + bias4.y, 0.f);
        o.z = fmaxf(az * 0.25f + bias4.z, 0.f);
        o.w = fmaxf(aw * 0.25f + bias4.w, 0.f);
        *(float4*)(out + (size_t)n * 64 + 4 * lane) = o;
    }
}

// ---------------- launch ----------------
extern "C" void kernel_launch(void* const* d_in, const int* in_sizes, int n_in,
                              void* d_out, int out_size, void* d_ws, size_t ws_size,
                              hipStream_t stream)
{
    const float* x   = (const float*)d_in[0];
    const int*   ei  = (const int*)d_in[1];
    const float* W1  = (const float*)d_in[4];
    const float* as1 = (const float*)d_in[5];
    const float* ad1 = (const float*)d_in[6];
    const float* b1  = (const float*)d_in[7];
    const float* W2  = (const float*)d_in[8];
    const float* as2 = (const float*)d_in[9];
    const float* ad2 = (const float*)d_in[10];
    const float* b2  = (const float*)d_in[11];

    const int E = in_sizes[1] / 2;
    const int N = N_NODES;
    const int NB = (N + 1023) / 1024;

    char* ws = (char*)d_ws;
    size_t off = 0;
    auto alloc = [&](size_t bytes) -> void* {
        void* p = ws + off;
        off = (off + bytes + 255) & ~(size_t)255;
        return p;
    };
    float* h      = (float*)alloc((size_t)N * 256 * 4);
    float* x1     = (float*)alloc((size_t)N * 64 * 4);
    float* asrc   = (float*)alloc((size_t)N * 4 * 4);
    float* adst   = (float*)alloc((size_t)N * 4 * 4);
    int*   cnt    = (int*)alloc((size_t)N * 4);
    int*   row    = (int*)alloc((size_t)(N + 1) * 4);
    int*   cursor = (int*)alloc((size_t)N * 4);
    int*   psrc   = (int*)alloc((size_t)E * 4);
    int*   excl   = (int*)alloc((size_t)N * 4);
    int*   bsum   = (int*)alloc(256 * 4);

    zero_k<<<(N + 255) / 256, 256, 0, stream>>>(cnt, N);
    hist_k<<<(E + 255) / 256, 256, 0, stream>>>(ei, cnt, E);
    scan1_k<<<NB, 1024, 0, stream>>>(cnt, excl, bsum, N);
    scan2_k<<<1, 64, 0, stream>>>(bsum, NB);
    scan3_k<<<(N + 256) / 256, 256, 0, stream>>>(excl, bsum, row, cursor, N, E);
    scatter_k<<<(E + 255) / 256, 256, 0, stream>>>(ei, cursor, psrc, E);

    dim3 ggrid((N + 127) / 128, 2);

    gemm_alpha2_k<<<ggrid, 256, 0, stream>>>(x, W1, as1, ad1, h, asrc, adst, N);
    aggregate2_k<<<(N + 3) / 4, 256, 0, stream>>>(h, asrc, adst, row, psrc, b1, x1, N);

    gemm_alpha2_k<<<ggrid, 256, 0, stream>>>(x1, W2, as2, ad2, h, asrc, adst, N);
    aggregate2_k<<<(N + 3) / 4, 256, 0, stream>>>(h, asrc, adst, row, psrc, b2, (float*)d_out, N);
}

// Round 4
// 291.359 us; speedup vs baseline: 2.3758x; 1.4369x over previous
//
#include <hip/hip_runtime.h>
#include <hip/hip_bf16.h>
#include <math.h>

#define N_NODES 50000
#define NEG_SLOPE 0.2f
#define EPS_DEN 1e-16f

// ---------------- prep: Wa[i][h] = sum_o W[i,h,o]*a[h,o] ----------------
// WaSD[i*8 + h] = src side, WaSD[i*8 + 4 + h] = dst side.
__global__ void __launch_bounds__(256) prep_k(
    const float* __restrict__ W, const float* __restrict__ aS,
    const float* __restrict__ aD, float* __restrict__ WaSD)
{
    int tid = threadIdx.x;
    int h = tid >> 6, i = tid & 63;
    const float* wrow = W + (size_t)i * 256 + h * 64;
    const float* as = aS + h * 64;
    const float* ad = aD + h * 64;
    float ws = 0.f, wd = 0.f;
    #pragma unroll 8
    for (int o = 0; o < 64; ++o) {
        float w = wrow[o];
        ws = fmaf(w, as[o], ws);
        wd = fmaf(w, ad[o], wd);
    }
    WaSD[i * 8 + h]     = ws;
    WaSD[i * 8 + 4 + h] = wd;
}

// ---------------- alpha: asrc/adst[n,h] = x[n,:] . Wa[:,h] ----------------
// 256 threads = 64 nodes/block; thread quarter q covers i = q*16..q*16+15.
__global__ void __launch_bounds__(256) alpha_k(
    const float* __restrict__ x, const float* __restrict__ WaSD,
    float* __restrict__ asrc, float* __restrict__ adst, int N)
{
    __shared__ float Wl[64 * 8];   // 2 KB
    int tid = threadIdx.x;
    if (tid < 256) { Wl[tid] = WaSD[tid]; Wl[256 + tid < 512 ? 256 + tid : 0] = WaSD[(256 + tid) & 511]; }
    // simpler: two explicit loads
    __syncthreads();

    int node = blockIdx.x * 64 + (tid >> 2);
    int q = tid & 3;
    if (node >= N) return;

    float pS[4] = {0.f, 0.f, 0.f, 0.f};
    float pD[4] = {0.f, 0.f, 0.f, 0.f};
    const float* xp = x + (size_t)node * 64 + q * 16;
    #pragma unroll
    for (int j = 0; j < 4; ++j) {
        float4 xv = *(const float4*)(xp + j * 4);
        float xr[4] = {xv.x, xv.y, xv.z, xv.w};
        #pragma unroll
        for (int u = 0; u < 4; ++u) {
            int i = q * 16 + j * 4 + u;
            float4 wS = *(const float4*)(Wl + i * 8);
            float4 wD = *(const float4*)(Wl + i * 8 + 4);
            pS[0] = fmaf(xr[u], wS.x, pS[0]); pS[1] = fmaf(xr[u], wS.y, pS[1]);
            pS[2] = fmaf(xr[u], wS.z, pS[2]); pS[3] = fmaf(xr[u], wS.w, pS[3]);
            pD[0] = fmaf(xr[u], wD.x, pD[0]); pD[1] = fmaf(xr[u], wD.y, pD[1]);
            pD[2] = fmaf(xr[u], wD.z, pD[2]); pD[3] = fmaf(xr[u], wD.w, pD[3]);
        }
    }
    #pragma unroll
    for (int off = 1; off <= 2; off <<= 1) {
        #pragma unroll
        for (int h = 0; h < 4; ++h) {
            pS[h] += __shfl_xor(pS[h], off);
            pD[h] += __shfl_xor(pD[h], off);
        }
    }
    if (q == 0) {
        *(float4*)(asrc + 4 * (size_t)node) = make_float4(pS[0], pS[1], pS[2], pS[3]);
        *(float4*)(adst + 4 * (size_t)node) = make_float4(pD[0], pD[1], pD[2], pD[3]);
    }
}

// ---------------- CSR build ----------------
__global__ void zero_k(int* __restrict__ p, int n) {
    int i = blockIdx.x * blockDim.x + threadIdx.x;
    if (i < n) p[i] = 0;
}

__global__ void hist_k(const int* __restrict__ ei, int* __restrict__ cnt, int E) {
    int e = blockIdx.x * blockDim.x + threadIdx.x;
    if (e < E) atomicAdd(&cnt[ei[E + e]], 1);
}

__global__ void __launch_bounds__(1024) scan1_k(
    const int* __restrict__ cnt, int* __restrict__ excl, int* __restrict__ bsum, int n)
{
    __shared__ int sd[1024];
    int tid = threadIdx.x;
    int i = blockIdx.x * 1024 + tid;
    int v = (i < n) ? cnt[i] : 0;
    sd[tid] = v;
    __syncthreads();
    for (int off = 1; off < 1024; off <<= 1) {
        int t = (tid >= off) ? sd[tid - off] : 0;
        __syncthreads();
        sd[tid] += t;
        __syncthreads();
    }
    if (i < n) excl[i] = sd[tid] - v;
    if (tid == 1023) bsum[blockIdx.x] = sd[1023];
}

__global__ void scan2_k(int* __restrict__ bsum, int nb) {
    if (threadIdx.x == 0 && blockIdx.x == 0) {
        int acc = 0;
        for (int i = 0; i < nb; ++i) { int t = bsum[i]; bsum[i] = acc; acc += t; }
    }
}

__global__ void scan3_k(const int* __restrict__ excl, const int* __restrict__ bsum,
                        int* __restrict__ row, int* __restrict__ cursor, int n, int E)
{
    int i = blockIdx.x * blockDim.x + threadIdx.x;
    if (i < n) {
        int r = excl[i] + bsum[i >> 10];
        row[i] = r;
        cursor[i] = r;
    }
    if (i == n) row[n] = E;
}

__global__ void scatter_k(const int* __restrict__ ei, int* __restrict__ cursor,
                          int* __restrict__ psrc, int E)
{
    int e = blockIdx.x * blockDim.x + threadIdx.x;
    if (e < E) {
        int d = ei[E + e];
        int pos = atomicAdd(&cursor[d], 1);
        psrc[pos] = ei[e];
    }
}

// ---------------- aggregate x[src] per head -> z[n, h*64+i] ----------------
// one wave per node; lane = input channel i. z[h] = 0.25/(s_h+eps) * sum_e w_eh x[src_e]
#define MAXDEG 256
__global__ void __launch_bounds__(256) aggregate3_k(
    const float* __restrict__ x, const float* __restrict__ asrc,
    const float* __restrict__ adst, const int* __restrict__ row,
    const int* __restrict__ psrc, float* __restrict__ z, int N)
{
    __shared__ float4 pL[4][MAXDEG];   // 16 KB
    __shared__ int    sI[4][MAXDEG];   //  4 KB
    const int wid  = threadIdx.x >> 6;
    const int lane = threadIdx.x & 63;
    const int n = blockIdx.x * 4 + wid;
    if (n >= N) return;
    const int rs = row[n], re = row[n + 1];
    const int deg = re - rs;

    const float4 ad = *(const float4*)(adst + 4 * (size_t)n);

    float m0 = -INFINITY, m1 = -INFINITY, m2 = -INFINITY, m3 = -INFINITY;
    float s0 = 0.f, s1 = 0.f, s2 = 0.f, s3 = 0.f;
    float a0 = 0.f, a1 = 0.f, a2 = 0.f, a3 = 0.f;

    if (deg <= MAXDEG) {
        for (int j = lane; j < deg; j += 64) {
            int s = psrc[rs + j];
            sI[wid][j] = s;
            float4 a = *(const float4*)(asrc + 4 * (size_t)s);
            float e0 = a.x + ad.x; e0 = e0 > 0.f ? e0 : NEG_SLOPE * e0;
            float e1 = a.y + ad.y; e1 = e1 > 0.f ? e1 : NEG_SLOPE * e1;
            float e2 = a.z + ad.z; e2 = e2 > 0.f ? e2 : NEG_SLOPE * e2;
            float e3 = a.w + ad.w; e3 = e3 > 0.f ? e3 : NEG_SLOPE * e3;
            pL[wid][j] = make_float4(e0, e1, e2, e3);
            m0 = fmaxf(m0, e0); m1 = fmaxf(m1, e1);
            m2 = fmaxf(m2, e2); m3 = fmaxf(m3, e3);
        }
        #pragma unroll
        for (int off = 32; off >= 1; off >>= 1) {
            m0 = fmaxf(m0, __shfl_xor(m0, off));
            m1 = fmaxf(m1, __shfl_xor(m1, off));
            m2 = fmaxf(m2, __shfl_xor(m2, off));
            m3 = fmaxf(m3, __shfl_xor(m3, off));
        }
        for (int j = lane; j < deg; j += 64) {
            float4 e = pL[wid][j];
            float4 p = make_float4(__expf(e.x - m0), __expf(e.y - m1),
                                   __expf(e.z - m2), __expf(e.w - m3));
            pL[wid][j] = p;
            s0 += p.x; s1 += p.y; s2 += p.z; s3 += p.w;
        }
        #pragma unroll
        for (int off = 32; off >= 1; off >>= 1) {
            s0 += __shfl_xor(s0, off);
            s1 += __shfl_xor(s1, off);
            s2 += __shfl_xor(s2, off);
            s3 += __shfl_xor(s3, off);
        }
        // weighted gather of x[src][lane]
        #pragma unroll 4
        for (int j = 0; j < deg; ++j) {
            int s = sI[wid][j];
            float4 p = pL[wid][j];
            float xv = x[(size_t)s * 64 + lane];
            a0 = fmaf(p.x, xv, a0);
            a1 = fmaf(p.y, xv, a1);
            a2 = fmaf(p.z, xv, a2);
            a3 = fmaf(p.w, xv, a3);
        }
    } else {
        // fallback (deg > 256): recompute paths, no LDS
        for (int idx = rs + lane; idx < re; idx += 64) {
            int s = psrc[idx];
            float4 a = *(const float4*)(asrc + 4 * (size_t)s);
            float e0 = a.x + ad.x; e0 = e0 > 0.f ? e0 : NEG_SLOPE * e0;
            float e1 = a.y + ad.y; e1 = e1 > 0.f ? e1 : NEG_SLOPE * e1;
            float e2 = a.z + ad.z; e2 = e2 > 0.f ? e2 : NEG_SLOPE * e2;
            float e3 = a.w + ad.w; e3 = e3 > 0.f ? e3 : NEG_SLOPE * e3;
            m0 = fmaxf(m0, e0); m1 = fmaxf(m1, e1);
            m2 = fmaxf(m2, e2); m3 = fmaxf(m3, e3);
        }
        #pragma unroll
        for (int off = 32; off >= 1; off >>= 1) {
            m0 = fmaxf(m0, __shfl_xor(m0, off));
            m1 = fmaxf(m1, __shfl_xor(m1, off));
            m2 = fmaxf(m2, __shfl_xor(m2, off));
            m3 = fmaxf(m3, __shfl_xor(m3, off));
        }
        for (int idx = rs + lane; idx < re; idx += 64) {
            int s = psrc[idx];
            float4 a = *(const float4*)(asrc + 4 * (size_t)s);
            float e0 = a.x + ad.x; e0 = e0 > 0.f ? e0 : NEG_SLOPE * e0;
            float e1 = a.y + ad.y; e1 = e1 > 0.f ? e1 : NEG_SLOPE * e1;
            float e2 = a.z + ad.z; e2 = e2 > 0.f ? e2 : NEG_SLOPE * e2;
            float e3 = a.w + ad.w; e3 = e3 > 0.f ? e3 : NEG_SLOPE * e3;
            s0 += __expf(e0 - m0); s1 += __expf(e1 - m1);
            s2 += __expf(e2 - m2); s3 += __expf(e3 - m3);
        }
        #pragma unroll
        for (int off = 32; off >= 1; off >>= 1) {
            s0 += __shfl_xor(s0, off);
            s1 += __shfl_xor(s1, off);
            s2 += __shfl_xor(s2, off);
            s3 += __shfl_xor(s3, off);
        }
        for (int idx = rs; idx < re; ++idx) {
            int s = psrc[idx];
            float4 a = *(const float4*)(asrc + 4 * (size_t)s);
            float e0 = a.x + ad.x; e0 = e0 > 0.f ? e0 : NEG_SLOPE * e0;
            float e1 = a.y + ad.y; e1 = e1 > 0.f ? e1 : NEG_SLOPE * e1;
            float e2 = a.z + ad.z; e2 = e2 > 0.f ? e2 : NEG_SLOPE * e2;
            float e3 = a.w + ad.w; e3 = e3 > 0.f ? e3 : NEG_SLOPE * e3;
            float xv = x[(size_t)s * 64 + lane];
            a0 = fmaf(__expf(e0 - m0), xv, a0);
            a1 = fmaf(__expf(e1 - m1), xv, a1);
            a2 = fmaf(__expf(e2 - m2), xv, a2);
            a3 = fmaf(__expf(e3 - m3), xv, a3);
        }
    }

    float i0 = 0.25f / (s0 + EPS_DEN), i1 = 0.25f / (s1 + EPS_DEN);
    float i2 = 0.25f / (s2 + EPS_DEN), i3 = 0.25f / (s3 + EPS_DEN);
    float* zp = z + (size_t)n * 256;
    zp[lane]       = a0 * i0;
    zp[64 + lane]  = a1 * i1;
    zp[128 + lane] = a2 * i2;
    zp[192 + lane] = a3 * i3;
}

// ---------------- zw: out[n,o] = relu( sum_{h,i} z[n,h,i] W[i,h,o] + b[o] ) ----------------
// tile 64 nodes x 64 cols, K=256 in 4 chunks of 64 (chunk c == head c).
__global__ void __launch_bounds__(256) zw_k(
    const float* __restrict__ z, const float* __restrict__ W,
    const float* __restrict__ bias, float* __restrict__ out, int N)
{
    __shared__ float zT[64 * 64];  // [k][n^swz] 16 KB
    __shared__ float Ws[64 * 64];  // [i][o]     16 KB
    const int tid = threadIdx.x;
    const int n0  = blockIdx.x * 64;

    const int rgrp = tid >> 4;            // 16 row groups x 4 rows
    const int cgrp = tid & 15;            // 16 col groups x 4 cols
    const int r4 = rgrp << 2, c4 = cgrp << 2;

    float acc[4][4];
    #pragma unroll
    for (int i = 0; i < 4; ++i)
        #pragma unroll
        for (int j = 0; j < 4; ++j) acc[i][j] = 0.f;

    for (int c = 0; c < 4; ++c) {
        __syncthreads();
        // stage z chunk transposed+swizzled: zT[k][n ^ swz(k)]
        #pragma unroll
        for (int it = 0; it < 4; ++it) {
            int idx = tid + 256 * it;          // 0..1023 float4
            int n   = idx >> 4;
            int k4  = (idx & 15) << 2;
            int gn  = n0 + n;
            float4 v = make_float4(0.f, 0.f, 0.f, 0.f);
            if (gn < N) v = *(const float4*)(z + (size_t)gn * 256 + c * 64 + k4);
            int nsw = n ^ (((k4 >> 2) & 7) << 2);
            zT[(k4 + 0) * 64 + nsw] = v.x;
            zT[(k4 + 1) * 64 + nsw] = v.y;
            zT[(k4 + 2) * 64 + nsw] = v.z;
            zT[(k4 + 3) * 64 + nsw] = v.w;
        }
        // stage W chunk: Ws[i][o] = W[i*256 + c*64 + o]
        #pragma unroll
        for (int it = 0; it < 4; ++it) {
            int idx = tid + 256 * it;
            int i   = idx >> 4;
            int o4  = (idx & 15) << 2;
            *(float4*)(Ws + i * 64 + o4) =
                *(const float4*)(W + (size_t)i * 256 + c * 64 + o4);
        }
        __syncthreads();

        #pragma unroll 8
        for (int k = 0; k < 64; ++k) {
            int sw = ((k >> 2) & 7) << 2;
            float4 zv = *(const float4*)(zT + k * 64 + (r4 ^ sw));
            float4 wv = *(const float4*)(Ws + k * 64 + c4);
            float zr[4] = {zv.x, zv.y, zv.z, zv.w};
            float wc[4] = {wv.x, wv.y, wv.z, wv.w};
            #pragma unroll
            for (int i = 0; i < 4; ++i)
                #pragma unroll
                for (int j = 0; j < 4; ++j)
                    acc[i][j] = fmaf(zr[i], wc[j], acc[i][j]);
        }
    }

    float4 b4 = *(const float4*)(bias + c4);
    #pragma unroll
    for (int i = 0; i < 4; ++i) {
        int gn = n0 + r4 + i;
        if (gn < N) {
            float4 o;
            o.x = fmaxf(acc[i][0] + b4.x, 0.f);
            o.y = fmaxf(acc[i][1] + b4.y, 0.f);
            o.z = fmaxf(acc[i][2] + b4.z, 0.f);
            o.w = fmaxf(acc[i][3] + b4.w, 0.f);
            *(float4*)(out + (size_t)gn * 64 + c4) = o;
        }
    }
}

// ---------------- launch ----------------
extern "C" void kernel_launch(void* const* d_in, const int* in_sizes, int n_in,
                              void* d_out, int out_size, void* d_ws, size_t ws_size,
                              hipStream_t stream)
{
    const float* x   = (const float*)d_in[0];
    const int*   ei  = (const int*)d_in[1];
    const float* W1  = (const float*)d_in[4];
    const float* as1 = (const float*)d_in[5];
    const float* ad1 = (const float*)d_in[6];
    const float* b1  = (const float*)d_in[7];
    const float* W2  = (const float*)d_in[8];
    const float* as2 = (const float*)d_in[9];
    const float* ad2 = (const float*)d_in[10];
    const float* b2  = (const float*)d_in[11];

    const int E = in_sizes[1] / 2;
    const int N = N_NODES;
    const int NB = (N + 1023) / 1024;

    char* ws = (char*)d_ws;
    size_t off = 0;
    auto alloc = [&](size_t bytes) -> void* {
        void* p = ws + off;
        off = (off + bytes + 255) & ~(size_t)255;
        return p;
    };
    float* z      = (float*)alloc((size_t)N * 256 * 4);  // 51.2 MB
    float* x1     = (float*)alloc((size_t)N * 64 * 4);   // 12.8 MB
    float* asrc   = (float*)alloc((size_t)N * 4 * 4);
    float* adst   = (float*)alloc((size_t)N * 4 * 4);
    float* WaSD   = (float*)alloc(64 * 8 * 4);
    int*   cnt    = (int*)alloc((size_t)N * 4);
    int*   row    = (int*)alloc((size_t)(N + 1) * 4);
    int*   cursor = (int*)alloc((size_t)N * 4);
    int*   psrc   = (int*)alloc((size_t)E * 4);
    int*   excl   = (int*)alloc((size_t)N * 4);
    int*   bsum   = (int*)alloc(256 * 4);

    // CSR (shared by both layers)
    zero_k<<<(N + 255) / 256, 256, 0, stream>>>(cnt, N);
    hist_k<<<(E + 255) / 256, 256, 0, stream>>>(ei, cnt, E);
    scan1_k<<<NB, 1024, 0, stream>>>(cnt, excl, bsum, N);
    scan2_k<<<1, 64, 0, stream>>>(bsum, NB);
    scan3_k<<<(N + 256) / 256, 256, 0, stream>>>(excl, bsum, row, cursor, N, E);
    scatter_k<<<(E + 255) / 256, 256, 0, stream>>>(ei, cursor, psrc, E);

    const int nblk64 = (N + 63) / 64;

    // layer 1
    prep_k<<<1, 256, 0, stream>>>(W1, as1, ad1, WaSD);
    alpha_k<<<nblk64, 256, 0, stream>>>(x, WaSD, asrc, adst, N);
    aggregate3_k<<<(N + 3) / 4, 256, 0, stream>>>(x, asrc, adst, row, psrc, z, N);
    zw_k<<<nblk64, 256, 0, stream>>>(z, W1, b1, x1, N);

    // layer 2
    prep_k<<<1, 256, 0, stream>>>(W2, as2, ad2, WaSD);
    alpha_k<<<nblk64, 256, 0, stream>>>(x1, WaSD, asrc, adst, N);
    aggregate3_k<<<(N + 3) / 4, 256, 0, stream>>>(x1, asrc, adst, row, psrc, z, N);
    zw_k<<<nblk64, 256, 0, stream>>>(z, W2, b2, (float*)d_out, N);
}

// Round 5
// 249.930 us; speedup vs baseline: 2.7696x; 1.1658x over previous
//
#include <hip/hip_runtime.h>
#include <hip/hip_bf16.h>
#include <math.h>

#define N_NODES 50000
#define NEG_SLOPE 0.2f
#define EPS_DEN 1e-16f

#define NBUCK 196          // ceil(N_NODES / 256)
#define NBLK  512          // edge-pass blocks

// ---------------- prep: Wa[i][h] = sum_o W[i,h,o]*a[h,o] ----------------
__global__ void __launch_bounds__(256) prep_k(
    const float* __restrict__ W, const float* __restrict__ aS,
    const float* __restrict__ aD, float* __restrict__ WaSD)
{
    int tid = threadIdx.x;
    int h = tid >> 6, i = tid & 63;
    const float* wrow = W + (size_t)i * 256 + h * 64;
    const float* as = aS + h * 64;
    const float* ad = aD + h * 64;
    float ws = 0.f, wd = 0.f;
    #pragma unroll 8
    for (int o = 0; o < 64; ++o) {
        float w = wrow[o];
        ws = fmaf(w, as[o], ws);
        wd = fmaf(w, ad[o], wd);
    }
    WaSD[i * 8 + h]     = ws;
    WaSD[i * 8 + 4 + h] = wd;
}

// ---------------- alpha: asrc/adst[n,h] = x[n,:] . Wa[:,h] ----------------
__global__ void __launch_bounds__(256) alpha_k(
    const float* __restrict__ x, const float* __restrict__ WaSD,
    float* __restrict__ asrc, float* __restrict__ adst, int N)
{
    __shared__ float Wl[64 * 8];   // 2 KB
    int tid = threadIdx.x;
    Wl[tid]       = WaSD[tid];
    Wl[tid + 256] = WaSD[tid + 256];
    __syncthreads();

    int node = blockIdx.x * 64 + (tid >> 2);
    int q = tid & 3;
    if (node >= N) return;

    float pS[4] = {0.f, 0.f, 0.f, 0.f};
    float pD[4] = {0.f, 0.f, 0.f, 0.f};
    const float* xp = x + (size_t)node * 64 + q * 16;
    #pragma unroll
    for (int j = 0; j < 4; ++j) {
        float4 xv = *(const float4*)(xp + j * 4);
        float xr[4] = {xv.x, xv.y, xv.z, xv.w};
        #pragma unroll
        for (int u = 0; u < 4; ++u) {
            int i = q * 16 + j * 4 + u;
            float4 wS = *(const float4*)(Wl + i * 8);
            float4 wD = *(const float4*)(Wl + i * 8 + 4);
            pS[0] = fmaf(xr[u], wS.x, pS[0]); pS[1] = fmaf(xr[u], wS.y, pS[1]);
            pS[2] = fmaf(xr[u], wS.z, pS[2]); pS[3] = fmaf(xr[u], wS.w, pS[3]);
            pD[0] = fmaf(xr[u], wD.x, pD[0]); pD[1] = fmaf(xr[u], wD.y, pD[1]);
            pD[2] = fmaf(xr[u], wD.z, pD[2]); pD[3] = fmaf(xr[u], wD.w, pD[3]);
        }
    }
    #pragma unroll
    for (int off = 1; off <= 2; off <<= 1) {
        #pragma unroll
        for (int h = 0; h < 4; ++h) {
            pS[h] += __shfl_xor(pS[h], off);
            pD[h] += __shfl_xor(pD[h], off);
        }
    }
    if (q == 0) {
        *(float4*)(asrc + 4 * (size_t)node) = make_float4(pS[0], pS[1], pS[2], pS[3]);
        *(float4*)(adst + 4 * (size_t)node) = make_float4(pD[0], pD[1], pD[2], pD[3]);
    }
}

// ---------------- CSR build ----------------
__global__ void zero_k(int* __restrict__ p, int n) {
    int i = blockIdx.x * blockDim.x + threadIdx.x;
    if (i < n) p[i] = 0;
}

// per-node histogram (global atomics) + per-block bucket histogram
__global__ void __launch_bounds__(256) hist_bucket_k(
    const int* __restrict__ ei, int* __restrict__ cnt, int* __restrict__ bh, int E)
{
    __shared__ int lh[NBUCK];
    int tid = threadIdx.x;
    for (int b = tid; b < NBUCK; b += 256) lh[b] = 0;
    __syncthreads();

    const int ch = (E + NBLK - 1) / NBLK;
    const int e0 = blockIdx.x * ch;
    const int e1 = min(e0 + ch, E);
    for (int e = e0 + tid; e < e1; e += 256) {
        int d = ei[E + e];
        atomicAdd(&cnt[d], 1);
        atomicAdd(&lh[d >> 8], 1);
    }
    __syncthreads();
    for (int b = tid; b < NBUCK; b += 256)
        bh[(size_t)b * NBLK + blockIdx.x] = lh[b];
}

__global__ void __launch_bounds__(1024) scan1_k(
    const int* __restrict__ cnt, int* __restrict__ excl, int* __restrict__ bsum, int n)
{
    __shared__ int sd[1024];
    int tid = threadIdx.x;
    int i = blockIdx.x * 1024 + tid;
    int v = (i < n) ? cnt[i] : 0;
    sd[tid] = v;
    __syncthreads();
    for (int off = 1; off < 1024; off <<= 1) {
        int t = (tid >= off) ? sd[tid - off] : 0;
        __syncthreads();
        sd[tid] += t;
        __syncthreads();
    }
    if (i < n) excl[i] = sd[tid] - v;
    if (tid == 1023) bsum[blockIdx.x] = sd[1023];
}

__global__ void scan2_k(int* __restrict__ bsum, int nb) {
    if (threadIdx.x == 0 && blockIdx.x == 0) {
        int acc = 0;
        for (int i = 0; i < nb; ++i) { int t = bsum[i]; bsum[i] = acc; acc += t; }
    }
}

__global__ void scan3_k(const int* __restrict__ excl, const int* __restrict__ bsum,
                        int* __restrict__ row, int n, int E)
{
    int i = blockIdx.x * blockDim.x + threadIdx.x;
    if (i < n) row[i] = excl[i] + bsum[i >> 10];
    if (i == n) row[n] = E;
}

// per-bucket exclusive scan over NBLK block counts -> absolute stage offsets
__global__ void __launch_bounds__(64) bscan_k(
    const int* __restrict__ bh, const int* __restrict__ row,
    int* __restrict__ boff)
{
    const int b = blockIdx.x;
    const int lane = threadIdx.x;
    int v[8];
    int base = b * NBLK;          // NBLK = 512 = 64 lanes * 8
    #pragma unroll
    for (int u = 0; u < 8; ++u) v[u] = bh[base + lane * 8 + u];
    int t = 0;
    #pragma unroll
    for (int u = 0; u < 8; ++u) t += v[u];
    // wave exclusive prefix of t
    int run = t;
    #pragma unroll
    for (int off = 1; off < 64; off <<= 1) {
        int u = __shfl_up(run, off);
        if (lane >= off) run += u;
    }
    int lane_base = row[b << 8] + run - t;
    #pragma unroll
    for (int u = 0; u < 8; ++u) {
        boff[base + lane * 8 + u] = lane_base;
        lane_base += v[u];
    }
}

// place edges into bucket-grouped staging (LDS cursors, no global atomics)
__global__ void __launch_bounds__(256) bplace_k(
    const int* __restrict__ ei, const int* __restrict__ boff,
    unsigned int* __restrict__ stage, int E)
{
    __shared__ int cur[NBUCK];
    int tid = threadIdx.x;
    for (int b = tid; b < NBUCK; b += 256)
        cur[b] = boff[(size_t)b * NBLK + blockIdx.x];
    __syncthreads();

    const int ch = (E + NBLK - 1) / NBLK;
    const int e0 = blockIdx.x * ch;
    const int e1 = min(e0 + ch, E);
    for (int e = e0 + tid; e < e1; e += 256) {
        int s = ei[e];
        int d = ei[E + e];
        int pos = atomicAdd(&cur[d >> 8], 1);
        stage[pos] = (unsigned int)s | ((unsigned int)(d & 255) << 16);
    }
}

// per-bucket local scatter: bucket b owns nodes [b*256, b*256+256) and
// psrc range [row[b*256], row[b*256+256)) -- all writes stay in that range.
__global__ void __launch_bounds__(256) bscatter_k(
    const unsigned int* __restrict__ stage, const int* __restrict__ row,
    int* __restrict__ psrc, int N)
{
    __shared__ int cur[256];
    const int b = blockIdx.x;
    const int tid = threadIdx.x;
    const int nb0 = b << 8;
    int node = nb0 + tid;
    cur[tid] = (node < N) ? row[node] : 0;
    __syncthreads();

    const int es = row[nb0];
    const int ee = row[min(nb0 + 256, N)];
    for (int idx = es + tid; idx < ee; idx += 256) {
        unsigned int v = stage[idx];
        int s  = v & 0xFFFF;
        int dl = (v >> 16) & 0xFF;
        int pos = atomicAdd(&cur[dl], 1);
        psrc[pos] = s;
    }
}

// ---------------- aggregate x[src] per head -> z[n, h*64+i] ----------------
#define MAXDEG 256
__global__ void __launch_bounds__(256) aggregate3_k(
    const float* __restrict__ x, const float* __restrict__ asrc,
    const float* __restrict__ adst, const int* __restrict__ row,
    const int* __restrict__ psrc, float* __restrict__ z, int N)
{
    __shared__ float4 pL[4][MAXDEG];   // 16 KB
    __shared__ int    sI[4][MAXDEG];   //  4 KB
    const int wid  = threadIdx.x >> 6;
    const int lane = threadIdx.x & 63;
    const int n = blockIdx.x * 4 + wid;
    if (n >= N) return;
    const int rs = row[n], re = row[n + 1];
    const int deg = re - rs;

    const float4 ad = *(const float4*)(adst + 4 * (size_t)n);

    float m0 = -INFINITY, m1 = -INFINITY, m2 = -INFINITY, m3 = -INFINITY;
    float s0 = 0.f, s1 = 0.f, s2 = 0.f, s3 = 0.f;
    float a0 = 0.f, a1 = 0.f, a2 = 0.f, a3 = 0.f;

    if (deg <= MAXDEG) {
        for (int j = lane; j < deg; j += 64) {
            int s = psrc[rs + j];
            sI[wid][j] = s;
            float4 a = *(const float4*)(asrc + 4 * (size_t)s);
            float e0 = a.x + ad.x; e0 = e0 > 0.f ? e0 : NEG_SLOPE * e0;
            float e1 = a.y + ad.y; e1 = e1 > 0.f ? e1 : NEG_SLOPE * e1;
            float e2 = a.z + ad.z; e2 = e2 > 0.f ? e2 : NEG_SLOPE * e2;
            float e3 = a.w + ad.w; e3 = e3 > 0.f ? e3 : NEG_SLOPE * e3;
            pL[wid][j] = make_float4(e0, e1, e2, e3);
            m0 = fmaxf(m0, e0); m1 = fmaxf(m1, e1);
            m2 = fmaxf(m2, e2); m3 = fmaxf(m3, e3);
        }
        #pragma unroll
        for (int off = 32; off >= 1; off >>= 1) {
            m0 = fmaxf(m0, __shfl_xor(m0, off));
            m1 = fmaxf(m1, __shfl_xor(m1, off));
            m2 = fmaxf(m2, __shfl_xor(m2, off));
            m3 = fmaxf(m3, __shfl_xor(m3, off));
        }
        for (int j = lane; j < deg; j += 64) {
            float4 e = pL[wid][j];
            float4 p = make_float4(__expf(e.x - m0), __expf(e.y - m1),
                                   __expf(e.z - m2), __expf(e.w - m3));
            pL[wid][j] = p;
            s0 += p.x; s1 += p.y; s2 += p.z; s3 += p.w;
        }
        #pragma unroll
        for (int off = 32; off >= 1; off >>= 1) {
            s0 += __shfl_xor(s0, off);
            s1 += __shfl_xor(s1, off);
            s2 += __shfl_xor(s2, off);
            s3 += __shfl_xor(s3, off);
        }
        #pragma unroll 4
        for (int j = 0; j < deg; ++j) {
            int s = sI[wid][j];
            float4 p = pL[wid][j];
            float xv = x[(size_t)s * 64 + lane];
            a0 = fmaf(p.x, xv, a0);
            a1 = fmaf(p.y, xv, a1);
            a2 = fmaf(p.z, xv, a2);
            a3 = fmaf(p.w, xv, a3);
        }
    } else {
        for (int idx = rs + lane; idx < re; idx += 64) {
            int s = psrc[idx];
            float4 a = *(const float4*)(asrc + 4 * (size_t)s);
            float e0 = a.x + ad.x; e0 = e0 > 0.f ? e0 : NEG_SLOPE * e0;
            float e1 = a.y + ad.y; e1 = e1 > 0.f ? e1 : NEG_SLOPE * e1;
            float e2 = a.z + ad.z; e2 = e2 > 0.f ? e2 : NEG_SLOPE * e2;
            float e3 = a.w + ad.w; e3 = e3 > 0.f ? e3 : NEG_SLOPE * e3;
            m0 = fmaxf(m0, e0); m1 = fmaxf(m1, e1);
            m2 = fmaxf(m2, e2); m3 = fmaxf(m3, e3);
        }
        #pragma unroll
        for (int off = 32; off >= 1; off >>= 1) {
            m0 = fmaxf(m0, __shfl_xor(m0, off));
            m1 = fmaxf(m1, __shfl_xor(m1, off));
            m2 = fmaxf(m2, __shfl_xor(m2, off));
            m3 = fmaxf(m3, __shfl_xor(m3, off));
        }
        for (int idx = rs + lane; idx < re; idx += 64) {
            int s = psrc[idx];
            float4 a = *(const float4*)(asrc + 4 * (size_t)s);
            float e0 = a.x + ad.x; e0 = e0 > 0.f ? e0 : NEG_SLOPE * e0;
            float e1 = a.y + ad.y; e1 = e1 > 0.f ? e1 : NEG_SLOPE * e1;
            float e2 = a.z + ad.z; e2 = e2 > 0.f ? e2 : NEG_SLOPE * e2;
            float e3 = a.w + ad.w; e3 = e3 > 0.f ? e3 : NEG_SLOPE * e3;
            s0 += __expf(e0 - m0); s1 += __expf(e1 - m1);
            s2 += __expf(e2 - m2); s3 += __expf(e3 - m3);
        }
        #pragma unroll
        for (int off = 32; off >= 1; off >>= 1) {
            s0 += __shfl_xor(s0, off);
            s1 += __shfl_xor(s1, off);
            s2 += __shfl_xor(s2, off);
            s3 += __shfl_xor(s3, off);
        }
        for (int idx = rs; idx < re; ++idx) {
            int s = psrc[idx];
            float4 a = *(const float4*)(asrc + 4 * (size_t)s);
            float e0 = a.x + ad.x; e0 = e0 > 0.f ? e0 : NEG_SLOPE * e0;
            float e1 = a.y + ad.y; e1 = e1 > 0.f ? e1 : NEG_SLOPE * e1;
            float e2 = a.z + ad.z; e2 = e2 > 0.f ? e2 : NEG_SLOPE * e2;
            float e3 = a.w + ad.w; e3 = e3 > 0.f ? e3 : NEG_SLOPE * e3;
            float xv = x[(size_t)s * 64 + lane];
            a0 = fmaf(__expf(e0 - m0), xv, a0);
            a1 = fmaf(__expf(e1 - m1), xv, a1);
            a2 = fmaf(__expf(e2 - m2), xv, a2);
            a3 = fmaf(__expf(e3 - m3), xv, a3);
        }
    }

    float i0 = 0.25f / (s0 + EPS_DEN), i1 = 0.25f / (s1 + EPS_DEN);
    float i2 = 0.25f / (s2 + EPS_DEN), i3 = 0.25f / (s3 + EPS_DEN);
    float* zp = z + (size_t)n * 256;
    zp[lane]       = a0 * i0;
    zp[64 + lane]  = a1 * i1;
    zp[128 + lane] = a2 * i2;
    zp[192 + lane] = a3 * i3;
}

// ---------------- zw: out[n,o] = relu( sum_{h,i} z[n,h,i] W[i,h,o] + b[o] ) ----------------
__global__ void __launch_bounds__(256) zw_k(
    const float* __restrict__ z, const float* __restrict__ W,
    const float* __restrict__ bias, float* __restrict__ out, int N)
{
    __shared__ float zT[64 * 64];  // [k][n^swz] 16 KB
    __shared__ float Ws[64 * 64];  // [i][o]     16 KB
    const int tid = threadIdx.x;
    const int n0  = blockIdx.x * 64;

    const int rgrp = tid >> 4;
    const int cgrp = tid & 15;
    const int r4 = rgrp << 2, c4 = cgrp << 2;

    float acc[4][4];
    #pragma unroll
    for (int i = 0; i < 4; ++i)
        #pragma unroll
        for (int j = 0; j < 4; ++j) acc[i][j] = 0.f;

    for (int c = 0; c < 4; ++c) {
        __syncthreads();
        #pragma unroll
        for (int it = 0; it < 4; ++it) {
            int idx = tid + 256 * it;
            int n   = idx >> 4;
            int k4  = (idx & 15) << 2;
            int gn  = n0 + n;
            float4 v = make_float4(0.f, 0.f, 0.f, 0.f);
            if (gn < N) v = *(const float4*)(z + (size_t)gn * 256 + c * 64 + k4);
            int nsw = n ^ (((k4 >> 2) & 7) << 2);
            zT[(k4 + 0) * 64 + nsw] = v.x;
            zT[(k4 + 1) * 64 + nsw] = v.y;
            zT[(k4 + 2) * 64 + nsw] = v.z;
            zT[(k4 + 3) * 64 + nsw] = v.w;
        }
        #pragma unroll
        for (int it = 0; it < 4; ++it) {
            int idx = tid + 256 * it;
            int i   = idx >> 4;
            int o4  = (idx & 15) << 2;
            *(float4*)(Ws + i * 64 + o4) =
                *(const float4*)(W + (size_t)i * 256 + c * 64 + o4);
        }
        __syncthreads();

        #pragma unroll 8
        for (int k = 0; k < 64; ++k) {
            int sw = ((k >> 2) & 7) << 2;
            float4 zv = *(const float4*)(zT + k * 64 + (r4 ^ sw));
            float4 wv = *(const float4*)(Ws + k * 64 + c4);
            float zr[4] = {zv.x, zv.y, zv.z, zv.w};
            float wc[4] = {wv.x, wv.y, wv.z, wv.w};
            #pragma unroll
            for (int i = 0; i < 4; ++i)
                #pragma unroll
                for (int j = 0; j < 4; ++j)
                    acc[i][j] = fmaf(zr[i], wc[j], acc[i][j]);
        }
    }

    float4 b4 = *(const float4*)(bias + c4);
    #pragma unroll
    for (int i = 0; i < 4; ++i) {
        int gn = n0 + r4 + i;
        if (gn < N) {
            float4 o;
            o.x = fmaxf(acc[i][0] + b4.x, 0.f);
            o.y = fmaxf(acc[i][1] + b4.y, 0.f);
            o.z = fmaxf(acc[i][2] + b4.z, 0.f);
            o.w = fmaxf(acc[i][3] + b4.w, 0.f);
            *(float4*)(out + (size_t)gn * 64 + c4) = o;
        }
    }
}

// ---------------- launch ----------------
extern "C" void kernel_launch(void* const* d_in, const int* in_sizes, int n_in,
                              void* d_out, int out_size, void* d_ws, size_t ws_size,
                              hipStream_t stream)
{
    const float* x   = (const float*)d_in[0];
    const int*   ei  = (const int*)d_in[1];
    const float* W1  = (const float*)d_in[4];
    const float* as1 = (const float*)d_in[5];
    const float* ad1 = (const float*)d_in[6];
    const float* b1  = (const float*)d_in[7];
    const float* W2  = (const float*)d_in[8];
    const float* as2 = (const float*)d_in[9];
    const float* ad2 = (const float*)d_in[10];
    const float* b2  = (const float*)d_in[11];

    const int E = in_sizes[1] / 2;
    const int N = N_NODES;
    const int NB = (N + 1023) / 1024;

    char* ws = (char*)d_ws;
    size_t off = 0;
    auto alloc = [&](size_t bytes) -> void* {
        void* p = ws + off;
        off = (off + bytes + 255) & ~(size_t)255;
        return p;
    };
    float*        z     = (float*)alloc((size_t)N * 256 * 4);  // 51.2 MB
    float*        x1    = (float*)alloc((size_t)N * 64 * 4);   // 12.8 MB
    float*        asrc  = (float*)alloc((size_t)N * 4 * 4);
    float*        adst  = (float*)alloc((size_t)N * 4 * 4);
    float*        WaSD  = (float*)alloc(64 * 8 * 4);
    int*          cnt   = (int*)alloc((size_t)N * 4);
    int*          row   = (int*)alloc((size_t)(N + 1) * 4);
    int*          psrc  = (int*)alloc((size_t)E * 4);
    int*          excl  = (int*)alloc((size_t)N * 4);
    int*          bsum  = (int*)alloc(256 * 4);
    int*          bh    = (int*)alloc((size_t)NBUCK * NBLK * 4);   // 401 KB
    int*          boff  = (int*)alloc((size_t)NBUCK * NBLK * 4);   // 401 KB
    unsigned int* stage = (unsigned int*)alloc((size_t)E * 4);     // 3.2 MB

    // CSR (shared by both layers)
    zero_k<<<(N + 255) / 256, 256, 0, stream>>>(cnt, N);
    hist_bucket_k<<<NBLK, 256, 0, stream>>>(ei, cnt, bh, E);
    scan1_k<<<NB, 1024, 0, stream>>>(cnt, excl, bsum, N);
    scan2_k<<<1, 64, 0, stream>>>(bsum, NB);
    scan3_k<<<(N + 256) / 256, 256, 0, stream>>>(excl, bsum, row, N, E);
    bscan_k<<<NBUCK, 64, 0, stream>>>(bh, row, boff);
    bplace_k<<<NBLK, 256, 0, stream>>>(ei, boff, stage, E);
    bscatter_k<<<NBUCK, 256, 0, stream>>>(stage, row, psrc, N);

    const int nblk64 = (N + 63) / 64;

    // layer 1
    prep_k<<<1, 256, 0, stream>>>(W1, as1, ad1, WaSD);
    alpha_k<<<nblk64, 256, 0, stream>>>(x, WaSD, asrc, adst, N);
    aggregate3_k<<<(N + 3) / 4, 256, 0, stream>>>(x, asrc, adst, row, psrc, z, N);
    zw_k<<<nblk64, 256, 0, stream>>>(z, W1, b1, x1, N);

    // layer 2
    prep_k<<<1, 256, 0, stream>>>(W2, as2, ad2, WaSD);
    alpha_k<<<nblk64, 256, 0, stream>>>(x1, WaSD, asrc, adst, N);
    aggregate3_k<<<(N + 3) / 4, 256, 0, stream>>>(x1, asrc, adst, row, psrc, z, N);
    zw_k<<<nblk64, 256, 0, stream>>>(z, W2, b2, (float*)d_out, N);
}